// Round 1
// baseline (343.363 us; speedup 1.0000x reference)
//
#include <hip/hip_runtime.h>

typedef __bf16 bf16x4 __attribute__((ext_vector_type(4)));
typedef __bf16 bf16x8 __attribute__((ext_vector_type(8)));
typedef float f32x4 __attribute__((ext_vector_type(4)));

#define N_HALF 4096
#define NT 8192
#define D 1024
#define TILE 128

// workspace layout (bytes)
#define WS_TB_OFF 0                              // bf16 total [8192*1024] = 16 MiB
#define WS_SQ_OFF (NT * D * 2)                   // float sq[8192]
#define WS_COLSUM_OFF (WS_SQ_OFF + NT * 4)       // float colsum[1024]
#define WS_SUMSQ_OFF (WS_COLSUM_OFF + D * 4)     // double
#define WS_RESULT_OFF (WS_SUMSQ_OFF + 8)         // double
#define WS_CEXP_OFF (WS_RESULT_OFF + 8)          // float[5]

__device__ __forceinline__ float wave_sum(float v) {
#pragma unroll
  for (int off = 32; off > 0; off >>= 1) v += __shfl_xor(v, off, 64);
  return v;
}

__device__ __forceinline__ float fast_exp2(float x) {
#if __has_builtin(__builtin_amdgcn_exp2f)
  return __builtin_amdgcn_exp2f(x);
#else
  return exp2f(x);
#endif
}

__device__ __forceinline__ void load_lds16(const void* gptr, void* ldsptr) {
  __builtin_amdgcn_global_load_lds(
      (const __attribute__((address_space(1))) void*)gptr,
      (__attribute__((address_space(3))) void*)ldsptr, 16, 0, 0);
}

// zero colsum[1024] + sumsq(2w) + result(2w) + cexp(5w) = 1033 words
__global__ void init_kernel(unsigned int* zbase) {
  for (int i = threadIdx.x; i < 1033; i += 256) zbase[i] = 0u;
}

// fp32 -> bf16 convert, per-row squared norm, global sum of squared norms
__global__ __launch_bounds__(256) void prep_kernel(const float* __restrict__ src,
                                                   const float* __restrict__ tgt,
                                                   __bf16* __restrict__ tb,
                                                   float* __restrict__ sq,
                                                   double* __restrict__ sumsq) {
  int wid = (int)((blockIdx.x * 256u + threadIdx.x) >> 6);  // row 0..8191
  int lane = threadIdx.x & 63;
  const float* rowp = (wid < N_HALF) ? (src + (size_t)wid * D)
                                     : (tgt + (size_t)(wid - N_HALF) * D);
  float acc = 0.f;
#pragma unroll
  for (int i = 0; i < 4; ++i) {
    int v4 = i * 64 + lane;  // float4 index within row
    float4 v = ((const float4*)rowp)[v4];
    bf16x4 o;
    o[0] = (__bf16)v.x; o[1] = (__bf16)v.y; o[2] = (__bf16)v.z; o[3] = (__bf16)v.w;
    *(bf16x4*)(tb + (size_t)wid * D + v4 * 4) = o;
    acc = fmaf(v.x, v.x, acc);
    acc = fmaf(v.y, v.y, acc);
    acc = fmaf(v.z, v.z, acc);
    acc = fmaf(v.w, v.w, acc);
  }
  acc = wave_sum(acc);
  if (lane == 0) {
    sq[wid] = acc;
    atomicAdd(sumsq, (double)acc);
  }
}

// column sums of the fp32 matrix (for ||sum_i x_i||^2)
__global__ __launch_bounds__(256) void colsum_kernel(const float* __restrict__ src,
                                                     const float* __restrict__ tgt,
                                                     float* __restrict__ colsum) {
  int t = threadIdx.x;
  int b = blockIdx.x;  // 64 blocks x 128 rows
  float acc[4] = {0.f, 0.f, 0.f, 0.f};
  for (int r = 0; r < 128; ++r) {
    int row = b * 128 + r;
    const float* rowp = (row < N_HALF) ? (src + (size_t)row * D)
                                       : (tgt + (size_t)(row - N_HALF) * D);
#pragma unroll
    for (int c = 0; c < 4; ++c) acc[c] += rowp[t + c * 256];
  }
#pragma unroll
  for (int c = 0; c < 4; ++c) atomicAdd(&colsum[t + c * 256], acc[c]);
}

// closed-form bandwidth -> 5 exp2 coefficients
__global__ void bw_kernel(const float* __restrict__ colsum,
                          const double* __restrict__ sumsq,
                          float* __restrict__ cexp) {
  __shared__ float red[4];
  int t = threadIdx.x;
  float s = 0.f;
#pragma unroll
  for (int c = 0; c < 4; ++c) {
    float v = colsum[t + c * 256];
    s = fmaf(v, v, s);
  }
  s = wave_sum(s);
  if ((t & 63) == 0) red[t >> 6] = s;
  __syncthreads();
  if (t == 0) {
    double s2 = (double)red[0] + red[1] + red[2] + red[3];
    double n = (double)NT;
    double suml2 = 2.0 * n * (*sumsq) - 2.0 * s2;
    double denom = n * n - n;
    double band = suml2 / denom / 4.0;  // KERNEL_MUL^(KERNEL_NUM//2) = 4
    for (int k = 0; k < 5; ++k)
      cexp[k] = (float)(-1.4426950408889634 / (band * (double)(1 << k)));
  }
}

// 128x128 tile MFMA GEMM over G = T T^t with fused 5-bandwidth RBF epilogue,
// signed (sigma_i sigma_j) reduction; upper-triangular tiles only (weight 2).
__global__ __launch_bounds__(256) void mmd_gemm(const __bf16* __restrict__ tb,
                                                const float* __restrict__ sq,
                                                const float* __restrict__ cexp,
                                                double* __restrict__ result) {
  int bx = blockIdx.x, by = blockIdx.y;
  if (by > bx) return;  // symmetry: G and sigma-sign are symmetric
  __shared__ __align__(16) __bf16 As[TILE * 32];
  __shared__ __align__(16) __bf16 Bs[TILE * 32];
  int tid = threadIdx.x;
  int w = tid >> 6, lane = tid & 63;
  int wy = w >> 1, wx = w & 1;  // 2x2 waves, 64x64 per wave
  int rowBase = by * TILE, colBase = bx * TILE;
  f32x4 acc[4][4] = {};

  // staging: each 1024B LDS chunk g covers 16 rows; lane l -> row 16g+l/4, 16B col chunk l%4
  int lrow = lane >> 2;
  int lcolb = (lane & 3) * 16;
  const char* tbb = (const char*)tb;
  size_t arow0 = (size_t)(rowBase + w * 16 + lrow) * 2048 + lcolb;
  size_t arow1 = (size_t)(rowBase + (w + 4) * 16 + lrow) * 2048 + lcolb;
  size_t brow0 = (size_t)(colBase + w * 16 + lrow) * 2048 + lcolb;
  size_t brow1 = (size_t)(colBase + (w + 4) * 16 + lrow) * 2048 + lcolb;
  char* AsB = (char*)As;
  char* BsB = (char*)Bs;
  // fragment read offsets (elements): row*(32) + quad*8
  int fra = (wy * 64 + (lane & 15)) * 32 + (lane >> 4) * 8;
  int frb = (wx * 64 + (lane & 15)) * 32 + (lane >> 4) * 8;

  for (int kk = 0; kk < 32; ++kk) {
    int k0b = kk * 64;  // 32 bf16 = 64 bytes per K-step
    load_lds16(tbb + arow0 + k0b, AsB + w * 1024);
    load_lds16(tbb + arow1 + k0b, AsB + (w + 4) * 1024);
    load_lds16(tbb + brow0 + k0b, BsB + w * 1024);
    load_lds16(tbb + brow1 + k0b, BsB + (w + 4) * 1024);
    __syncthreads();
    bf16x8 a[4], b[4];
#pragma unroll
    for (int mt = 0; mt < 4; ++mt) a[mt] = *(const bf16x8*)(As + fra + mt * 16 * 32);
#pragma unroll
    for (int nt = 0; nt < 4; ++nt) b[nt] = *(const bf16x8*)(Bs + frb + nt * 16 * 32);
#pragma unroll
    for (int mt = 0; mt < 4; ++mt)
#pragma unroll
      for (int nt = 0; nt < 4; ++nt)
        acc[mt][nt] =
            __builtin_amdgcn_mfma_f32_16x16x32_bf16(a[mt], b[nt], acc[mt][nt], 0, 0, 0);
    __syncthreads();
  }

  // epilogue: l2 = max(sq_i + sq_j - 2 g, 0); sum_k exp2(l2 * cexp_k)
  float c0 = cexp[0], c1 = cexp[1], c2 = cexp[2], c3 = cexp[3], c4 = cexp[4];
  int colg = colBase + wx * 64 + (lane & 15);
  int rquad = (lane >> 4) * 4;
  float sqc[4];
#pragma unroll
  for (int nt = 0; nt < 4; ++nt) sqc[nt] = sq[colg + nt * 16];
  float wsum = 0.f;
#pragma unroll
  for (int mt = 0; mt < 4; ++mt) {
    int rb = rowBase + wy * 64 + mt * 16 + rquad;
    float srs[4] = {sq[rb], sq[rb + 1], sq[rb + 2], sq[rb + 3]};
#pragma unroll
    for (int nt = 0; nt < 4; ++nt) {
      f32x4 v = acc[mt][nt];
#pragma unroll
      for (int r = 0; r < 4; ++r) {
        float l2 = fmaxf(fmaf(-2.f, v[r], srs[r] + sqc[nt]), 0.f);
        float e = fast_exp2(l2 * c0) + fast_exp2(l2 * c1) + fast_exp2(l2 * c2) +
                  fast_exp2(l2 * c3) + fast_exp2(l2 * c4);
        wsum += e;
      }
    }
  }
  float sgn = ((by < 32) == (bx < 32)) ? 1.f : -1.f;
  float wgt = (bx == by) ? 1.f : 2.f;
  wsum *= sgn * wgt;
  wsum = wave_sum(wsum);
  if (lane == 0) atomicAdd(result, (double)wsum);
}

__global__ void finalize_kernel(const double* __restrict__ result, float* __restrict__ out) {
  if (threadIdx.x == 0) out[0] = (float)(*result / ((double)N_HALF * (double)N_HALF));
}

extern "C" void kernel_launch(void* const* d_in, const int* in_sizes, int n_in,
                              void* d_out, int out_size, void* d_ws, size_t ws_size,
                              hipStream_t stream) {
  (void)in_sizes; (void)n_in; (void)out_size; (void)ws_size;
  const float* src = (const float*)d_in[0];
  const float* tgt = (const float*)d_in[1];
  char* ws = (char*)d_ws;
  __bf16* tb = (__bf16*)(ws + WS_TB_OFF);
  float* sq = (float*)(ws + WS_SQ_OFF);
  float* colsum = (float*)(ws + WS_COLSUM_OFF);
  double* sumsq = (double*)(ws + WS_SUMSQ_OFF);
  double* result = (double*)(ws + WS_RESULT_OFF);
  float* cexp = (float*)(ws + WS_CEXP_OFF);

  init_kernel<<<1, 256, 0, stream>>>((unsigned int*)(ws + WS_COLSUM_OFF));
  prep_kernel<<<NT / 4, 256, 0, stream>>>(src, tgt, tb, sq, sumsq);
  colsum_kernel<<<64, 256, 0, stream>>>(src, tgt, colsum);
  bw_kernel<<<1, 256, 0, stream>>>(colsum, sumsq, cexp);
  mmd_gemm<<<dim3(64, 64), 256, 0, stream>>>(tb, sq, cexp, result);
  finalize_kernel<<<1, 64, 0, stream>>>(result, (float*)d_out);
}

// Round 2
// 182.523 us; speedup vs baseline: 1.8812x; 1.8812x over previous
//
#include <hip/hip_runtime.h>

typedef __bf16 bf16x4 __attribute__((ext_vector_type(4)));
typedef __bf16 bf16x8 __attribute__((ext_vector_type(8)));
typedef float f32x4 __attribute__((ext_vector_type(4)));

#define N_HALF 4096
#define NT 8192
#define D 1024
#define TILE 128

// workspace layout (bytes)
#define WS_TB_OFF 0                                    // bf16 [8192*1024] = 16 MiB
#define WS_SQ_OFF (NT * D * 2)                         // float sq[8192]
#define WS_COLPART_OFF (WS_SQ_OFF + NT * 4)            // float colpart[512][1024] = 2 MiB
#define WS_COLSUM2_OFF (WS_COLPART_OFF + 512 * D * 4)  // float[16]
#define WS_C4_OFF (WS_COLSUM2_OFF + 64)                // float[1]
#define WS_PARTIAL_OFF (WS_C4_OFF + 64)                // float partial[4096] = 16 KiB

__device__ __forceinline__ float wave_sum(float v) {
#pragma unroll
  for (int off = 32; off > 0; off >>= 1) v += __shfl_xor(v, off, 64);
  return v;
}

__device__ __forceinline__ float fast_exp2(float x) {
#if __has_builtin(__builtin_amdgcn_exp2f)
  return __builtin_amdgcn_exp2f(x);
#else
  return exp2f(x);
#endif
}

__device__ __forceinline__ void load_lds16(const void* gptr, void* ldsptr) {
  __builtin_amdgcn_global_load_lds(
      (const __attribute__((address_space(1))) void*)gptr,
      (__attribute__((address_space(3))) void*)ldsptr, 16, 0, 0);
}

// fp32 -> bf16 convert, per-row squared norm, per-block column partial sums.
// No global atomics: colpart[block][1024] plain stores.
__global__ __launch_bounds__(256) void prep_kernel(const float* __restrict__ src,
                                                   const float* __restrict__ tgt,
                                                   __bf16* __restrict__ tb,
                                                   float* __restrict__ sq,
                                                   float* __restrict__ colpart) {
  int w = threadIdx.x >> 6, lane = threadIdx.x & 63;
  int rbase = blockIdx.x * 16 + w * 4;  // 512 blocks x 16 rows
  f32x4 csum[4] = {};
#pragma unroll
  for (int r = 0; r < 4; ++r) {
    int row = rbase + r;
    const float* rowp = (row < N_HALF) ? (src + (size_t)row * D)
                                       : (tgt + (size_t)(row - N_HALF) * D);
    float acc = 0.f;
#pragma unroll
    for (int i = 0; i < 4; ++i) {
      int v4 = i * 64 + lane;
      float4 v = ((const float4*)rowp)[v4];
      bf16x4 o;
      o[0] = (__bf16)v.x; o[1] = (__bf16)v.y; o[2] = (__bf16)v.z; o[3] = (__bf16)v.w;
      *(bf16x4*)(tb + (size_t)row * D + v4 * 4) = o;
      acc = fmaf(v.x, v.x, acc);
      acc = fmaf(v.y, v.y, acc);
      acc = fmaf(v.z, v.z, acc);
      acc = fmaf(v.w, v.w, acc);
      csum[i][0] += v.x; csum[i][1] += v.y; csum[i][2] += v.z; csum[i][3] += v.w;
    }
    acc = wave_sum(acc);
    if (lane == 0) sq[row] = acc;
  }
  __shared__ f32x4 cred[4][256];  // 16 KiB
#pragma unroll
  for (int i = 0; i < 4; ++i) cred[w][i * 64 + lane] = csum[i];
  __syncthreads();
  int t = threadIdx.x;
  f32x4 s = cred[0][t] + cred[1][t] + cred[2][t] + cred[3][t];
  ((f32x4*)colpart)[(size_t)blockIdx.x * 256 + t] = s;
}

// reduce colpart over 512 blocks -> per-64-column sum-of-squares (16 blocks)
__global__ __launch_bounds__(256) void colreduce_kernel(const float* __restrict__ colpart,
                                                        float* __restrict__ colsum2) {
  int t = threadIdx.x;
  int c = blockIdx.x * 64 + (t & 63);
  int p0 = (t >> 6) * 128;
  float s = 0.f;
  for (int p = 0; p < 128; ++p) s += colpart[(size_t)(p0 + p) * D + c];
  __shared__ float red[4][64];
  red[t >> 6][t & 63] = s;
  __syncthreads();
  if (t < 64) {
    float cs = red[0][t] + red[1][t] + red[2][t] + red[3][t];
    float v = wave_sum(cs * cs);
    if (t == 0) colsum2[blockIdx.x] = v;
  }
}

// closed-form bandwidth -> single exp2 coefficient c4 (smallest-magnitude exponent)
__global__ void bw_kernel(const float* __restrict__ sq, const float* __restrict__ colsum2,
                          float* __restrict__ c4) {
  int t = threadIdx.x;  // 256
  float s = 0.f;
  for (int k = 0; k < 32; ++k) s += sq[t + 256 * k];
  s = wave_sum(s);
  __shared__ float red[4];
  if ((t & 63) == 0) red[t >> 6] = s;
  __syncthreads();
  if (t == 0) {
    double ssq = (double)red[0] + red[1] + red[2] + red[3];
    double s2 = 0.0;
    for (int i = 0; i < 16; ++i) s2 += (double)colsum2[i];
    double n = (double)NT;
    double suml2 = 2.0 * n * ssq - 2.0 * s2;
    double band = suml2 / (n * n - n) / 4.0;  // / KERNEL_MUL^(KERNEL_NUM//2)
    c4[0] = (float)(-1.4426950408889634 / (band * 16.0));
  }
}

// 128x128 tile, BK=64, XOR-swizzled LDS, fused RBF epilogue via t-powers,
// per-block partial store (no global atomics). Upper-triangular tiles only.
__global__ __launch_bounds__(256, 4) void mmd_gemm(const __bf16* __restrict__ tb,
                                                   const float* __restrict__ sq,
                                                   const float* __restrict__ c4p,
                                                   float* __restrict__ partial) {
  int bx = blockIdx.x, by = blockIdx.y;
  int pidx = by * 64 + bx;
  if (by > bx) {
    if (threadIdx.x == 0) partial[pidx] = 0.f;
    return;
  }
  __shared__ __align__(16) char As[TILE * 128];  // 128 rows x 128 B (64 bf16)
  __shared__ __align__(16) char Bs[TILE * 128];
  __shared__ float redw[4];
  int tid = threadIdx.x, w = tid >> 6, lane = tid & 63;
  int wy = w >> 1, wx = w & 1;  // 2x2 waves, 64x64 per wave
  int rowBase = by * TILE, colBase = bx * TILE;
  f32x4 acc[4][4] = {};

  // staging: call j of wave w stages rows 32w+8j..+8; lane l -> row +l/8, phys chunk l%8
  // LDS[row][phys] = global[row][phys ^ (row&7)]  (swizzle applied on SOURCE address)
  int l8 = lane >> 3, lc = lane & 7, swz = lc ^ l8;
  const char* tbb = (const char*)tb;
  size_t ag = (size_t)(rowBase + 32 * w + l8) * 2048 + (size_t)swz * 16;
  size_t bg = (size_t)(colBase + 32 * w + l8) * 2048 + (size_t)swz * 16;
  char* Asl = As + w * 4096;
  char* Bsl = Bs + w * 4096;

  // fragment addressing: row = tile64 + mt*16 + (lane&15); row&7 == lane&7
  int r16 = lane & 15, q = lane >> 4, rx = lane & 7;
  int arow = (wy * 64 + r16) * 128;
  int brow = (wx * 64 + r16) * 128;
  int c0 = (q ^ rx) * 16;        // k-step s=0: logical chunk q
  int c1 = ((4 ^ q) ^ rx) * 16;  // k-step s=1: logical chunk 4+q

  for (int kk = 0; kk < 16; ++kk) {
    size_t ko = (size_t)kk * 128;
#pragma unroll
    for (int j = 0; j < 4; ++j) {
      load_lds16(tbb + ag + ko + (size_t)j * 8 * 2048, Asl + j * 1024);
      load_lds16(tbb + bg + ko + (size_t)j * 8 * 2048, Bsl + j * 1024);
    }
    __syncthreads();
    {
      bf16x8 a[4], b[4];
#pragma unroll
      for (int mt = 0; mt < 4; ++mt) a[mt] = *(const bf16x8*)(As + arow + mt * 2048 + c0);
#pragma unroll
      for (int nt = 0; nt < 4; ++nt) b[nt] = *(const bf16x8*)(Bs + brow + nt * 2048 + c0);
#pragma unroll
      for (int mt = 0; mt < 4; ++mt)
#pragma unroll
        for (int nt = 0; nt < 4; ++nt)
          acc[mt][nt] =
              __builtin_amdgcn_mfma_f32_16x16x32_bf16(a[mt], b[nt], acc[mt][nt], 0, 0, 0);
    }
    {
      bf16x8 a[4], b[4];
#pragma unroll
      for (int mt = 0; mt < 4; ++mt) a[mt] = *(const bf16x8*)(As + arow + mt * 2048 + c1);
#pragma unroll
      for (int nt = 0; nt < 4; ++nt) b[nt] = *(const bf16x8*)(Bs + brow + nt * 2048 + c1);
#pragma unroll
      for (int mt = 0; mt < 4; ++mt)
#pragma unroll
        for (int nt = 0; nt < 4; ++nt)
          acc[mt][nt] =
              __builtin_amdgcn_mfma_f32_16x16x32_bf16(a[mt], b[nt], acc[mt][nt], 0, 0, 0);
    }
    __syncthreads();
  }

  // epilogue: l2 = max(sq_i + sq_j - 2 g, 0); sum_k t^(2^k), t = exp2(l2*c4)
  float c4 = *c4p;
  int colg = colBase + wx * 64 + r16;
  int rquad = q * 4;
  float sqc[4];
#pragma unroll
  for (int nt = 0; nt < 4; ++nt) sqc[nt] = sq[colg + nt * 16];
  float wsum = 0.f;
#pragma unroll
  for (int mt = 0; mt < 4; ++mt) {
    int rb = rowBase + wy * 64 + mt * 16 + rquad;
    float srs[4] = {sq[rb], sq[rb + 1], sq[rb + 2], sq[rb + 3]};
#pragma unroll
    for (int nt = 0; nt < 4; ++nt) {
      f32x4 v = acc[mt][nt];
#pragma unroll
      for (int r = 0; r < 4; ++r) {
        float l2 = fmaxf(fmaf(-2.f, v[r], srs[r] + sqc[nt]), 0.f);
        float tt = fast_exp2(l2 * c4);
        float t2 = tt * tt, t4 = t2 * t2, t8 = t4 * t4, t16 = t8 * t8;
        wsum += ((tt + t2) + (t4 + t8)) + t16;
      }
    }
  }
  wsum = wave_sum(wsum);
  if (lane == 0) redw[w] = wsum;
  __syncthreads();
  if (tid == 0) {
    float sgn = ((by < 32) == (bx < 32)) ? 1.f : -1.f;
    float wgt = (bx == by) ? 1.f : 2.f;
    partial[pidx] = (redw[0] + redw[1] + redw[2] + redw[3]) * sgn * wgt;
  }
}

__global__ void finalize_kernel(const float* __restrict__ partial, float* __restrict__ out) {
  int t = threadIdx.x;  // 256
  double s = 0.0;
  for (int i = 0; i < 16; ++i) s += (double)partial[t + 256 * i];
#pragma unroll
  for (int off = 32; off > 0; off >>= 1) s += __shfl_xor(s, off, 64);
  __shared__ double red[4];
  if ((t & 63) == 0) red[t >> 6] = s;
  __syncthreads();
  if (t == 0) out[0] = (float)((red[0] + red[1] + red[2] + red[3]) /
                               ((double)N_HALF * (double)N_HALF));
}

extern "C" void kernel_launch(void* const* d_in, const int* in_sizes, int n_in,
                              void* d_out, int out_size, void* d_ws, size_t ws_size,
                              hipStream_t stream) {
  (void)in_sizes; (void)n_in; (void)out_size; (void)ws_size;
  const float* src = (const float*)d_in[0];
  const float* tgt = (const float*)d_in[1];
  char* ws = (char*)d_ws;
  __bf16* tb = (__bf16*)(ws + WS_TB_OFF);
  float* sq = (float*)(ws + WS_SQ_OFF);
  float* colpart = (float*)(ws + WS_COLPART_OFF);
  float* colsum2 = (float*)(ws + WS_COLSUM2_OFF);
  float* c4 = (float*)(ws + WS_C4_OFF);
  float* partial = (float*)(ws + WS_PARTIAL_OFF);

  prep_kernel<<<512, 256, 0, stream>>>(src, tgt, tb, sq, colpart);
  colreduce_kernel<<<16, 256, 0, stream>>>(colpart, colsum2);
  bw_kernel<<<1, 256, 0, stream>>>(sq, colsum2, c4);
  mmd_gemm<<<dim3(64, 64), 256, 0, stream>>>(tb, sq, c4, partial);
  finalize_kernel<<<1, 256, 0, stream>>>(partial, (float*)d_out);
}

// Round 6
// 130.739 us; speedup vs baseline: 2.6263x; 1.3961x over previous
//
#include <hip/hip_runtime.h>

typedef float f32x4 __attribute__((ext_vector_type(4)));
typedef int i32x4v __attribute__((ext_vector_type(4)));
typedef int i32x8 __attribute__((ext_vector_type(8)));

#define N_HALF 4096
#define NT 8192
#define D 1024
#define TILE 128
#define NBLK 2080  // 64*65/2 triangular tiles

// workspace layout (bytes)
#define WS_TB_OFF 0                                    // fp8 [8192*1024] = 8 MiB
#define WS_SQQ_OFF (NT * D)                            // float sqq[8192] (quantized norms)
#define WS_SQE_OFF (WS_SQQ_OFF + NT * 4)               // float sqe[8192] (exact norms)
#define WS_COLPART_OFF (WS_SQE_OFF + NT * 4)           // float colpart[512][1024] = 2 MiB
#define WS_COLSUM2_OFF (WS_COLPART_OFF + 512 * D * 4)  // float[257]
#define WS_C4_OFF (WS_COLSUM2_OFF + 2048)              // float[1]
#define WS_PARTIAL_OFF (WS_C4_OFF + 64)                // float partial[2080]

// ---- compile-time XCD-locality block map (validated: round5 ≡ round3 output) --
struct BlockMap {
  unsigned short by[NBLK];
  unsigned short bx[NBLK];
  constexpr BlockMap() : by(), bx() {
    const int G[8][5] = {{17, 18, 19, 21, -1}, {22, 23, 24, 25, -1},
                         {26, 28, 29, 30, -1}, {31, 32, 33, 34, -1},
                         {0, 1, 2, 3, 4},      {5, 6, 7, 8, 9},
                         {10, 11, 12, 14, 20}, {13, 15, 16, 27, 35}};
    unsigned short sby[8][264] = {}, sbx[8][264] = {};
    int len[8] = {};
    for (int x = 0; x < 8; ++x)
      for (int gi = 0; gi < 5; ++gi) {
        int s = G[x][gi];
        if (s < 0) continue;
        int SX = 0;
        while ((SX + 1) * (SX + 2) / 2 <= s) ++SX;
        int SY = s - SX * (SX + 1) / 2;
        for (int u = 0; u < 8; ++u)
          for (int v = 0; v < 8; ++v) {
            int r = 8 * SY + u, c = 8 * SX + v;
            if (r <= c) {
              sby[x][len[x]] = (unsigned short)r;
              sbx[x][len[x]] = (unsigned short)c;
              ++len[x];
            }
          }
      }
    unsigned short pby[64] = {}, pbx[64] = {};
    int ns = 0;
    for (int x = 0; x < 8; ++x)
      for (int j = 260; j < len[x]; ++j) { pby[ns] = sby[x][j]; pbx[ns] = sbx[x][j]; ++ns; }
    int sp = 0;
    for (int x = 0; x < 8; ++x)
      for (int j = 0; j < 260; ++j) {
        int b = 8 * j + x;
        if (j < len[x]) { by[b] = sby[x][j]; bx[b] = sbx[x][j]; }
        else { by[b] = pby[sp]; bx[b] = pbx[sp]; ++sp; }
      }
  }
};
__constant__ BlockMap d_bmap = BlockMap();
// -----------------------------------------------------------------------------

__device__ __forceinline__ float wave_sum(float v) {
#pragma unroll
  for (int off = 32; off > 0; off >>= 1) v += __shfl_xor(v, off, 64);
  return v;
}

__device__ __forceinline__ float fast_exp2(float x) {
#if __has_builtin(__builtin_amdgcn_exp2f)
  return __builtin_amdgcn_exp2f(x);
#else
  return exp2f(x);
#endif
}

__device__ __forceinline__ void load_lds16(const void* gptr, void* ldsptr) {
  __builtin_amdgcn_global_load_lds(
      (const __attribute__((address_space(1))) void*)gptr,
      (__attribute__((address_space(3))) void*)ldsptr, 16, 0, 0);
}

// fp32 -> fp8 e4m3 quantize, quantized + exact row norms, per-block column partials.
__global__ __launch_bounds__(256) void prep_kernel(const float* __restrict__ src,
                                                   const float* __restrict__ tgt,
                                                   unsigned int* __restrict__ tb8,
                                                   float* __restrict__ sqq,
                                                   float* __restrict__ sqe,
                                                   float* __restrict__ colpart) {
  int w = threadIdx.x >> 6, lane = threadIdx.x & 63;
  int rbase = blockIdx.x * 16 + w * 4;  // 512 blocks x 16 rows
  f32x4 csum[4] = {};
#pragma unroll
  for (int r = 0; r < 4; ++r) {
    int row = rbase + r;
    const float* rowp = (row < N_HALF) ? (src + (size_t)row * D)
                                       : (tgt + (size_t)(row - N_HALF) * D);
    float accq = 0.f, acce = 0.f;
#pragma unroll
    for (int i = 0; i < 4; ++i) {
      int v4 = i * 64 + lane;
      float4 v = ((const float4*)rowp)[v4];
      int pk = __builtin_amdgcn_cvt_pk_fp8_f32(v.x, v.y, 0, false);
      pk = __builtin_amdgcn_cvt_pk_fp8_f32(v.z, v.w, pk, true);
      tb8[(size_t)row * 256 + v4] = (unsigned int)pk;
      float q0 = __builtin_amdgcn_cvt_f32_fp8(pk, 0);
      float q1 = __builtin_amdgcn_cvt_f32_fp8(pk, 1);
      float q2 = __builtin_amdgcn_cvt_f32_fp8(pk, 2);
      float q3 = __builtin_amdgcn_cvt_f32_fp8(pk, 3);
      accq = fmaf(q0, q0, accq); accq = fmaf(q1, q1, accq);
      accq = fmaf(q2, q2, accq); accq = fmaf(q3, q3, accq);
      acce = fmaf(v.x, v.x, acce); acce = fmaf(v.y, v.y, acce);
      acce = fmaf(v.z, v.z, acce); acce = fmaf(v.w, v.w, acce);
      csum[i][0] += v.x; csum[i][1] += v.y; csum[i][2] += v.z; csum[i][3] += v.w;
    }
    accq = wave_sum(accq);
    acce = wave_sum(acce);
    if (lane == 0) { sqq[row] = accq; sqe[row] = acce; }
  }
  __shared__ f32x4 cred[4][256];
#pragma unroll
  for (int i = 0; i < 4; ++i) cred[w][i * 64 + lane] = csum[i];
  __syncthreads();
  int t = threadIdx.x;
  f32x4 s = cred[0][t] + cred[1][t] + cred[2][t] + cred[3][t];
  ((f32x4*)colpart)[(size_t)blockIdx.x * 256 + t] = s;
}

// blocks 0..255: 4 columns each -> full column sums over 512 parts, squared, summed.
// block 256: ssq = sum of exact row norms.  [ssq reduction indices FIXED]
__global__ __launch_bounds__(256) void colred_kernel(const float* __restrict__ colpart,
                                                     const float* __restrict__ sqe,
                                                     float* __restrict__ colsum2) {
  int b = blockIdx.x, t = threadIdx.x;
  __shared__ float red[256];
  if (b < 256) {
    int c = b * 4 + (t & 3);
    float s = 0.f;
    for (int p = (t >> 2); p < 512; p += 64) s += colpart[(size_t)p * D + c];
    red[t] = s;
    __syncthreads();
    if (t < 4) {
      float cs = 0.f;
      for (int g = 0; g < 64; ++g) cs += red[g * 4 + t];
      red[t] = cs * cs;  // lane t only reads slots ≡ t (mod 4): no cross-lane hazard
    }
    __syncthreads();
    if (t == 0) colsum2[b] = red[0] + red[1] + red[2] + red[3];
  } else {
    float s = 0.f;
    for (int k = 0; k < 32; ++k) s += sqe[t + 256 * k];
    s = wave_sum(s);
    if ((t & 63) == 0) red[t >> 6] = s;  // writes red[0..3]
    __syncthreads();
    // FIX (was red[0]+red[64]+red[128]+red[192] -> garbage, rounds 3-5 failure)
    if (t == 0) colsum2[256] = red[0] + red[1] + red[2] + red[3];
  }
}

// closed-form bandwidth -> single exp2 coefficient
__global__ void bw_kernel(const float* __restrict__ colsum2, float* __restrict__ c4) {
  int t = threadIdx.x;  // 256
  float s = wave_sum(colsum2[t]);
  __shared__ float red[4];
  if ((t & 63) == 0) red[t >> 6] = s;
  __syncthreads();
  if (t == 0) {
    double b2 = (double)red[0] + red[1] + red[2] + red[3];
    double ssq = (double)colsum2[256];
    double n = (double)NT;
    double suml2 = 2.0 * n * ssq - 2.0 * b2;
    double band = suml2 / (n * n - n) / 4.0;  // / KERNEL_MUL^(KERNEL_NUM//2)
    c4[0] = (float)(-1.4426950408889634 / (band * 16.0));
  }
}

// 128x128 tile MX-fp8 GEMM (16x16x128, unit e8m0 scales), XOR-swizzled LDS,
// quantized-norm RBF epilogue, XCD-locality map, per-block partial store.
__global__ __launch_bounds__(256, 3) void mmd_gemm(const unsigned char* __restrict__ tb8,
                                                   const float* __restrict__ sqq,
                                                   const float* __restrict__ c4p,
                                                   float* __restrict__ partial) {
  int bid = blockIdx.x;
  int by = d_bmap.by[bid], bx = d_bmap.bx[bid];  // by <= bx
  __shared__ __align__(16) char As[TILE * 128];  // 128 rows x 128 B fp8
  __shared__ __align__(16) char Bs[TILE * 128];
  __shared__ float redw[4];
  int tid = threadIdx.x, w = tid >> 6, lane = tid & 63;
  int wy = w >> 1, wx = w & 1;  // 2x2 waves, 64x64 per wave
  int rowBase = by * TILE, colBase = bx * TILE;
  f32x4 acc[4][4] = {};

  // staging: wave w, call j covers rows 32w+8j+[0,8); lane l -> row +(l>>3),
  // phys chunk l&7, source chunk (l&7)^(l>>3)   (LDS[r][p]=glob[r][p^(r&7)])
  int l8 = lane >> 3, lc = lane & 7, swz = lc ^ l8;
  const char* tbb = (const char*)tb8;
  size_t ag = (size_t)(rowBase + 32 * w + l8) * 1024 + (size_t)swz * 16;
  size_t bg = (size_t)(colBase + 32 * w + l8) * 1024 + (size_t)swz * 16;
  char* Asl = As + w * 4096;
  char* Bsl = Bs + w * 4096;

  // fragment: row m = tile64 + mt*16 + (lane&15); lane's K-window (lane>>4)*32 B
  int r16 = lane & 15, q = lane >> 4, rx7 = lane & 7;
  int arowb = (wy * 64 + r16) * 128;
  int browb = (wx * 64 + r16) * 128;
  int ch0 = ((2 * q) ^ rx7) * 16;
  int ch1 = ((2 * q + 1) ^ rx7) * 16;

  for (int kk = 0; kk < 8; ++kk) {
    size_t ko = (size_t)kk * 128;
#pragma unroll
    for (int j = 0; j < 4; ++j) {
      load_lds16(tbb + ag + ko + (size_t)j * 8192, Asl + j * 1024);
      load_lds16(tbb + bg + ko + (size_t)j * 8192, Bsl + j * 1024);
    }
    __syncthreads();
    i32x8 af[4], bf[4];
#pragma unroll
    for (int mt = 0; mt < 4; ++mt) {
      const char* p = As + arowb + mt * 2048;
      i32x4v lo = *(const i32x4v*)(p + ch0);
      i32x4v hi = *(const i32x4v*)(p + ch1);
      af[mt] = (i32x8){lo[0], lo[1], lo[2], lo[3], hi[0], hi[1], hi[2], hi[3]};
    }
#pragma unroll
    for (int nt = 0; nt < 4; ++nt) {
      const char* p = Bs + browb + nt * 2048;
      i32x4v lo = *(const i32x4v*)(p + ch0);
      i32x4v hi = *(const i32x4v*)(p + ch1);
      bf[nt] = (i32x8){lo[0], lo[1], lo[2], lo[3], hi[0], hi[1], hi[2], hi[3]};
    }
#pragma unroll
    for (int mt = 0; mt < 4; ++mt)
#pragma unroll
      for (int nt = 0; nt < 4; ++nt)
        acc[mt][nt] = __builtin_amdgcn_mfma_scale_f32_16x16x128_f8f6f4(
            af[mt], bf[nt], acc[mt][nt], 0, 0, 0, 0x7f7f7f7f, 0, 0x7f7f7f7f);
    __syncthreads();
  }

  // epilogue: l2 = max(sqq_i + sqq_j - 2 g, 0) = |Q(x_i)-Q(x_j)|^2 exactly;
  // row-separable quantization bias cancels via sum(sigma)=0.
  float c4 = c4p[0];
  int colg = colBase + wx * 64 + r16;
  int rquad = q * 4;
  float sqc[4];
#pragma unroll
  for (int nt = 0; nt < 4; ++nt) sqc[nt] = sqq[colg + nt * 16];
  float wsum = 0.f;
#pragma unroll
  for (int mt = 0; mt < 4; ++mt) {
    int rb = rowBase + wy * 64 + mt * 16 + rquad;
    float srs[4] = {sqq[rb], sqq[rb + 1], sqq[rb + 2], sqq[rb + 3]};
#pragma unroll
    for (int nt = 0; nt < 4; ++nt) {
      f32x4 v = acc[mt][nt];
#pragma unroll
      for (int r = 0; r < 4; ++r) {
        float l2 = fmaxf(fmaf(-2.f, v[r], srs[r] + sqc[nt]), 0.f);
        float tt = fast_exp2(l2 * c4);
        float t2 = tt * tt, t4 = t2 * t2, t8 = t4 * t4, t16 = t8 * t8;
        wsum += ((tt + t2) + (t4 + t8)) + t16;
      }
    }
  }
  wsum = wave_sum(wsum);
  if (lane == 0) redw[w] = wsum;
  __syncthreads();
  if (tid == 0) {
    float sgn = ((by < 32) == (bx < 32)) ? 1.f : -1.f;
    float wgt = (bx == by) ? 1.f : 2.f;
    partial[bid] = (redw[0] + redw[1] + redw[2] + redw[3]) * sgn * wgt;
  }
}

__global__ void finalize_kernel(const float* __restrict__ partial, float* __restrict__ out) {
  int t = threadIdx.x;  // 256
  double s = 0.0;
  for (int k = 0; k < 9; ++k) {
    int i = t + 256 * k;
    if (i < NBLK) s += (double)partial[i];
  }
#pragma unroll
  for (int off = 32; off > 0; off >>= 1) s += __shfl_xor(s, off, 64);
  __shared__ double red[4];
  if ((t & 63) == 0) red[t >> 6] = s;
  __syncthreads();
  if (t == 0) out[0] = (float)((red[0] + red[1] + red[2] + red[3]) /
                               ((double)N_HALF * (double)N_HALF));
}

extern "C" void kernel_launch(void* const* d_in, const int* in_sizes, int n_in,
                              void* d_out, int out_size, void* d_ws, size_t ws_size,
                              hipStream_t stream) {
  (void)in_sizes; (void)n_in; (void)out_size; (void)ws_size;
  const float* src = (const float*)d_in[0];
  const float* tgt = (const float*)d_in[1];
  char* ws = (char*)d_ws;
  unsigned int* tb8 = (unsigned int*)(ws + WS_TB_OFF);
  float* sqq = (float*)(ws + WS_SQQ_OFF);
  float* sqe = (float*)(ws + WS_SQE_OFF);
  float* colpart = (float*)(ws + WS_COLPART_OFF);
  float* colsum2 = (float*)(ws + WS_COLSUM2_OFF);
  float* c4 = (float*)(ws + WS_C4_OFF);
  float* partial = (float*)(ws + WS_PARTIAL_OFF);

  prep_kernel<<<512, 256, 0, stream>>>(src, tgt, tb8, sqq, sqe, colpart);
  colred_kernel<<<257, 256, 0, stream>>>(colpart, sqe, colsum2);
  bw_kernel<<<1, 256, 0, stream>>>(colsum2, c4);
  mmd_gemm<<<NBLK, 256, 0, stream>>>((const unsigned char*)tb8, sqq, c4, partial);
  finalize_kernel<<<1, 256, 0, stream>>>(partial, (float*)d_out);
}